// Round 7
// baseline (622.751 us; speedup 1.0000x reference)
//
#include <hip/hip_runtime.h>
#include <hip/hip_bf16.h>

// ObjectSelector: fused MLP -> segment softmax -> segment-weighted embedding.
// Algebra: logit_i = x2_i . u_{s_i} + c_{s_i}   (u_s = Wk @ q_s, c_s = bk.q_s, /16 folded in)
//          emb_s   = (sum_i e_i x2_i)/den @ Wv + bv     (linearity of V-projection)
// kA computes GEMM1/GEMM2 TRANSPOSED (x^T = W^T @ obj^T); persistent blocks
// (4 contiguous tiles each, XCD-chunked) pipeline tile k+1's staging loads
// under tile k's compute; Y/D segment reduce is register-resident from the
// GEMM2 accumulator (masked fma + shfl_xor tree + one atomic per element).
// 3 barriers per tile. R3's reduce bug (short-circuited shfl reading an
// inactive lane for run-start detection) is fixed via unconditional shfl.

typedef __attribute__((ext_vector_type(8))) short bf16x8;
typedef __attribute__((ext_vector_type(4))) float f32x4;
typedef __attribute__((ext_vector_type(4))) short s16x4;

__device__ __forceinline__ float b2f(short s) {
    unsigned int u = ((unsigned int)(unsigned short)s) << 16;
    float f;
    __builtin_memcpy(&f, &u, 4);
    return f;
}
__device__ __forceinline__ short f2b(float x) {
    __hip_bfloat16 h = __float2bfloat16(x);
    short s;
    __builtin_memcpy(&s, &h, 2);
    return s;
}
__device__ __forceinline__ unsigned pack2(float a, float b) {
    return ((unsigned)(unsigned short)f2b(a)) | (((unsigned)(unsigned short)f2b(b)) << 16);
}
__device__ __forceinline__ f32x4 vmax0(f32x4 v) {
    f32x4 r;
    r[0] = fmaxf(v[0], 0.f); r[1] = fmaxf(v[1], 0.f);
    r[2] = fmaxf(v[2], 0.f); r[3] = fmaxf(v[3], 0.f);
    return r;
}

#define MFMA16(a, b, c) __builtin_amdgcn_mfma_f32_16x16x32_bf16(a, b, c, 0, 0, 0)
#define SWZ(row) (((row) & 7) << 4)   // XOR-swizzle on 16B chunks (G4 bank-conflict fix)

// ---------------------------------------------------------------------------
// prep0: weights -> bf16.
//  W0f: frag-ordered W0^T: i = (((w*4+mh)*4+ks)*64+lane)*8+e
//       value = W0[k][h], h=w*64+mh*16+(lane&15), k=ks*32+(lane>>4)*8+e
//  W1f: frag-ordered W1^T: i = (((w*4+mh)*8+ks)*64+lane)*8+e  (same mapping, K=256)
//  Wqt[n][k] (256x256), Wkvb straight copy (256x512)   (for kPrep1)
// ---------------------------------------------------------------------------
__global__ void kPrep0(const float* __restrict__ W0, const float* __restrict__ W1,
                       const float* __restrict__ Wkv, const float* __restrict__ Wq,
                       short* __restrict__ W0f, short* __restrict__ W1f,
                       short* __restrict__ Wkvb, short* __restrict__ Wqt) {
    int i = blockIdx.x * 256 + threadIdx.x;  // grid covers 131072
    if (i < 32768) {
        int e = i & 7, lane = (i >> 3) & 63, ks = (i >> 9) & 3, mh = (i >> 11) & 3, wv = (i >> 13) & 3;
        int h = wv * 64 + mh * 16 + (lane & 15);
        int k = ks * 32 + (lane >> 4) * 8 + e;
        W0f[i] = f2b(W0[k * 256 + h]);
    }
    if (i < 65536) {
        int e = i & 7, lane = (i >> 3) & 63, ks = (i >> 9) & 7, mh = (i >> 12) & 3, wv = (i >> 14) & 3;
        int h = wv * 64 + mh * 16 + (lane & 15);
        int k = ks * 32 + (lane >> 4) * 8 + e;
        W1f[i] = f2b(W1[k * 256 + h]);
        int n = i >> 8, kk = i & 255;
        Wqt[i] = f2b(Wq[kk * 256 + n]);
    }
    if (i < 131072) Wkvb[i] = f2b(Wkv[i]);
}

// ---------------------------------------------------------------------------
// prep1: per 64 context rows: q = ctx@Wq + bq; c = (q.bk)/16; u = (q@Wk^T)/16
// ---------------------------------------------------------------------------
__global__ __launch_bounds__(256) void kPrep1(
        const float* __restrict__ context, const short* __restrict__ Wqt,
        const float* __restrict__ bq, const short* __restrict__ Wkvb,
        const float* __restrict__ bkv, float* __restrict__ u_ws,
        float* __restrict__ c_ws) {
    __shared__ short cbuf[64 * 256];
    __shared__ float pl[4][64];
    const int t = threadIdx.x, w = t >> 6, l = t & 63;
    const int lo = l & 15, hi = l >> 4;
    const int base = blockIdx.x * 64;

    const float* src = context + (size_t)base * 256;
#pragma unroll
    for (int i = 0; i < 16; ++i) {
        int fi = (t + i * 256) * 4;
        float4 v = *(const float4*)(src + fi);
        int row = fi >> 8, col = fi & 255;
        int byte = (row << 9) + (col << 1);
        byte ^= SWZ(row);
        s16x4 pk;
        pk[0] = f2b(v.x); pk[1] = f2b(v.y); pk[2] = f2b(v.z); pk[3] = f2b(v.w);
        *(s16x4*)((char*)cbuf + byte) = pk;
    }
    __syncthreads();

    f32x4 acc[4][4] = {};
    const short* wqb = Wqt + (size_t)(w * 64 + lo) * 256 + hi * 8;
#pragma unroll
    for (int ks = 0; ks < 8; ++ks) {
        bf16x8 a[4], b[4];
#pragma unroll
        for (int m = 0; m < 4; ++m) {
            int row = m * 16 + lo;
            int byte = (row << 9) + ks * 64 + hi * 16;
            byte ^= SWZ(row);
            a[m] = *(const bf16x8*)((const char*)cbuf + byte);
        }
#pragma unroll
        for (int n = 0; n < 4; ++n) b[n] = *(const bf16x8*)(wqb + n * 16 * 256 + ks * 32);
#pragma unroll
        for (int m = 0; m < 4; ++m)
#pragma unroll
            for (int n = 0; n < 4; ++n) acc[m][n] = MFMA16(a[m], b[n], acc[m][n]);
    }
    __syncthreads();

    float bqv[4];
#pragma unroll
    for (int n = 0; n < 4; ++n) bqv[n] = bq[w * 64 + n * 16 + lo];
#pragma unroll
    for (int m = 0; m < 4; ++m)
#pragma unroll
        for (int n = 0; n < 4; ++n)
#pragma unroll
            for (int j = 0; j < 4; ++j) {
                float q = acc[m][n][j] + bqv[n];
                int row = m * 16 + hi * 4 + j;
                int col = w * 64 + n * 16 + lo;
                int byte = (row << 9) + (col << 1);
                byte ^= SWZ(row);
                *(short*)((char*)cbuf + byte) = f2b(q);
            }
    __syncthreads();

    {
        float p = 0.f;
#pragma unroll
        for (int j = 0; j < 8; ++j) {
            int col = w * 64 + j * 8;
            int byte = (l << 9) + (col << 1);
            byte ^= SWZ(l);
            bf16x8 xv = *(const bf16x8*)((const char*)cbuf + byte);
            const float* bp = bkv + col;
            p += b2f(xv[0]) * bp[0] + b2f(xv[1]) * bp[1] + b2f(xv[2]) * bp[2] + b2f(xv[3]) * bp[3]
               + b2f(xv[4]) * bp[4] + b2f(xv[5]) * bp[5] + b2f(xv[6]) * bp[6] + b2f(xv[7]) * bp[7];
        }
        pl[w][l] = p;
    }
    __syncthreads();
    if (t < 64) c_ws[base + t] = (pl[0][t] + pl[1][t] + pl[2][t] + pl[3][t]) * 0.0625f;

#pragma unroll
    for (int m = 0; m < 4; ++m)
#pragma unroll
        for (int n = 0; n < 4; ++n) acc[m][n] = (f32x4){0.f, 0.f, 0.f, 0.f};
    const short* wkb = Wkvb + (size_t)(w * 64 + lo) * 512 + hi * 8;
#pragma unroll
    for (int ks = 0; ks < 8; ++ks) {
        bf16x8 a[4], b[4];
#pragma unroll
        for (int m = 0; m < 4; ++m) {
            int row = m * 16 + lo;
            int byte = (row << 9) + ks * 64 + hi * 16;
            byte ^= SWZ(row);
            a[m] = *(const bf16x8*)((const char*)cbuf + byte);
        }
#pragma unroll
        for (int n = 0; n < 4; ++n) b[n] = *(const bf16x8*)(wkb + n * 16 * 512 + ks * 32);
#pragma unroll
        for (int m = 0; m < 4; ++m)
#pragma unroll
            for (int n = 0; n < 4; ++n) acc[m][n] = MFMA16(a[m], b[n], acc[m][n]);
    }
#pragma unroll
    for (int m = 0; m < 4; ++m)
#pragma unroll
        for (int n = 0; n < 4; ++n)
#pragma unroll
            for (int j = 0; j < 4; ++j) {
                int s = base + m * 16 + hi * 4 + j;
                int col = w * 64 + n * 16 + lo;
                u_ws[(size_t)s * 256 + col] = acc[m][n][j] * 0.0625f;
            }
}

// ---------------------------------------------------------------------------
// kernel A (persistent, transposed-MFMA, register-resident reduce):
//  4 contiguous tiles/block; staging for tile k+1 issued during tile k.
//  acc[mh][nn]: lane holds x2 for m = nn*16+(l&15), h = w*64+mh*16+(l>>4)*4+j.
// LDS: bufIn 16K [0,16K) | x1 32K [16K,48K) | pl.  3 barriers/tile.
// ---------------------------------------------------------------------------
__global__ __launch_bounds__(256, 3) void kA(
        const float* __restrict__ objects, const int* __restrict__ segids,
        const short* __restrict__ W0f, const short* __restrict__ W1f,
        const float* __restrict__ b0, const float* __restrict__ b1,
        const float* __restrict__ u_ws, const float* __restrict__ c_ws,
        float* __restrict__ e_ws, float* __restrict__ Y, float* __restrict__ D) {
    __shared__ char smem[49152];
    __shared__ float pl[4][64];
    char* bufIn = smem;           // objects bf16 [64][128]
    char* x1b   = smem + 16384;   // x1 bf16 [64][256]

    const int t = threadIdx.x, w = t >> 6, l = t & 63;
    const int lo = l & 15, hi = l >> 4;
    // XCD-chunked persistent assignment: 4 contiguous tiles per block
    const int bswz = (blockIdx.x & 7) * (gridDim.x >> 3) + (blockIdx.x >> 3);
    const int tid0 = bswz * 4;

    // prologue: stage tile 0 into packed regs
    uint2 stg[8];
    {
        const float* src = objects + (size_t)tid0 * 64 * 128;
#pragma unroll
        for (int i = 0; i < 8; ++i) {
            int fi = (t + i * 256) * 4;
            float4 v = *(const float4*)(src + fi);
            stg[i].x = pack2(v.x, v.y);
            stg[i].y = pack2(v.z, v.w);
        }
    }
    int sid_cur = segids[(size_t)tid0 * 64 + l];

    for (int k = 0; k < 4; ++k) {
        const size_t base_row = (size_t)(tid0 + k) * 64;
        const int sid_l = sid_cur;

        // write staged tile to bufIn (swizzled)
#pragma unroll
        for (int i = 0; i < 8; ++i) {
            int fi = (t + i * 256) * 4;
            int row = fi >> 7, col = fi & 127;
            int byte = (row << 8) + (col << 1);
            byte ^= SWZ(row);
            *(uint2*)(bufIn + byte) = stg[i];
        }
        __syncthreads();  // barrier A: bufIn ready

        // issue next-tile staging loads (latency hides under GEMM1+GEMM2)
        if (k < 3) {
            const float* nsrc = objects + (base_row + 64) * 128;
#pragma unroll
            for (int i = 0; i < 8; ++i) {
                int fi = (t + i * 256) * 4;
                float4 v = *(const float4*)(nsrc + fi);
                stg[i].x = pack2(v.x, v.y);
                stg[i].y = pack2(v.z, v.w);
            }
            sid_cur = segids[base_row + 64 + l];
        }

        // GEMM1 (transposed): x1^T = W0^T @ obj^T
        f32x4 acc[4][4] = {};
#pragma unroll
        for (int ks = 0; ks < 4; ++ks) {
            bf16x8 av[4], bv[4];
#pragma unroll
            for (int mh = 0; mh < 4; ++mh)
                av[mh] = *(const bf16x8*)(W0f + ((((w * 4 + mh) * 4 + ks) << 9) + (l << 3)));
#pragma unroll
            for (int nn = 0; nn < 4; ++nn) {
                int m = nn * 16 + lo;
                int byte = (m << 8) + (ks << 6) + (hi << 4);
                byte ^= SWZ(m);
                bv[nn] = *(const bf16x8*)(bufIn + byte);
            }
            __builtin_amdgcn_s_setprio(1);
#pragma unroll
            for (int mh = 0; mh < 4; ++mh)
#pragma unroll
                for (int nn = 0; nn < 4; ++nn) acc[mh][nn] = MFMA16(av[mh], bv[nn], acc[mh][nn]);
            __builtin_amdgcn_s_setprio(0);
        }

        // epilogue 1: x1[m][h] = relu(x + b0) — vector ops, b64 stores
#pragma unroll
        for (int mh = 0; mh < 4; ++mh) {
            f32x4 bb = *(const f32x4*)(b0 + w * 64 + mh * 16 + hi * 4);
#pragma unroll
            for (int nn = 0; nn < 4; ++nn) {
                f32x4 v = vmax0(acc[mh][nn] + bb);
                int m = nn * 16 + lo;
                int byte = (m << 9) + ((w * 64 + mh * 16 + hi * 4) << 1);
                byte ^= SWZ(m);
                uint2 pk;
                pk.x = pack2(v[0], v[1]);
                pk.y = pack2(v[2], v[3]);
                *(uint2*)(x1b + byte) = pk;
            }
        }
        __syncthreads();  // barrier B: x1 ready; bufIn reads done

        // GEMM2 (transposed): x2^T = W1^T @ x1^T
#pragma unroll
        for (int mh = 0; mh < 4; ++mh)
#pragma unroll
            for (int nn = 0; nn < 4; ++nn) acc[mh][nn] = (f32x4){0.f, 0.f, 0.f, 0.f};
#pragma unroll
        for (int ks = 0; ks < 8; ++ks) {
            bf16x8 av[4], bv[4];
#pragma unroll
            for (int mh = 0; mh < 4; ++mh)
                av[mh] = *(const bf16x8*)(W1f + ((((w * 4 + mh) * 8 + ks) << 9) + (l << 3)));
#pragma unroll
            for (int nn = 0; nn < 4; ++nn) {
                int m = nn * 16 + lo;
                int byte = (m << 9) + (ks << 6) + (hi << 4);
                byte ^= SWZ(m);
                bv[nn] = *(const bf16x8*)(x1b + byte);
            }
            __builtin_amdgcn_s_setprio(1);
#pragma unroll
            for (int mh = 0; mh < 4; ++mh)
#pragma unroll
                for (int nn = 0; nn < 4; ++nn) acc[mh][nn] = MFMA16(av[mh], bv[nn], acc[mh][nn]);
            __builtin_amdgcn_s_setprio(0);
        }

        // epilogue 2: bias+relu in acc (vector), fused logit partials
        int sids[4];
#pragma unroll
        for (int nn = 0; nn < 4; ++nn) sids[nn] = __shfl(sid_l, nn * 16 + lo);
        f32x4 pacc[4] = {};
#pragma unroll
        for (int mh = 0; mh < 4; ++mh) {
            f32x4 bb = *(const f32x4*)(b1 + w * 64 + mh * 16 + hi * 4);
#pragma unroll
            for (int nn = 0; nn < 4; ++nn) {
                f32x4 u4 = *(const f32x4*)(u_ws + (size_t)sids[nn] * 256 + w * 64 + mh * 16 + hi * 4);
                f32x4 v = vmax0(acc[mh][nn] + bb);
                acc[mh][nn] = v;
                pacc[nn] += v * u4;
            }
        }
#pragma unroll
        for (int nn = 0; nn < 4; ++nn) {
            float p = (pacc[nn][0] + pacc[nn][1]) + (pacc[nn][2] + pacc[nn][3]);
            p += __shfl_xor(p, 16);
            p += __shfl_xor(p, 32);
            if (hi == 0) pl[w][nn * 16 + lo] = p;
        }
        __syncthreads();  // barrier C: pl published; x1/bufIn free

        // every wave computes all 64 e's redundantly
        const float logit = pl[0][l] + pl[1][l] + pl[2][l] + pl[3][l] + c_ws[sid_l];
        const float e_l = __expf(logit);  // logits tiny: no max-subtraction needed
        if (w == 0) e_ws[base_row + l] = e_l;

        float e_nn[4];
#pragma unroll
        for (int nn = 0; nn < 4; ++nn) e_nn[nn] = __shfl(e_l, nn * 16 + lo);

        // run-start detection: unconditional shfl (ALL lanes active — R3 bug fix)
        const int sid_prev = __shfl(sid_l, (l > 0) ? (l - 1) : 0);
        const bool is_start = (l == 0) || (sid_l != sid_prev);
        unsigned long long bm = __ballot(is_start);
        while (bm) {
            const int r0 = __ffsll(bm) - 1;
            bm &= bm - 1;
            const int s = __shfl(sid_l, r0);
            float em[4];
#pragma unroll
            for (int nn = 0; nn < 4; ++nn) em[nn] = (sids[nn] == s) ? e_nn[nn] : 0.f;

            float dsum = (em[0] + em[1]) + (em[2] + em[3]);
            dsum += __shfl_xor(dsum, 1);
            dsum += __shfl_xor(dsum, 2);
            dsum += __shfl_xor(dsum, 4);
            dsum += __shfl_xor(dsum, 8);
            if (t == 0) atomicAdd(D + s, dsum);

            float* yp = Y + (size_t)s * 256 + w * 64 + hi * 4;
#pragma unroll
            for (int mh = 0; mh < 4; ++mh)
#pragma unroll
                for (int j = 0; j < 4; ++j) {
                    float v = em[0] * acc[mh][0][j] + em[1] * acc[mh][1][j]
                            + em[2] * acc[mh][2][j] + em[3] * acc[mh][3][j];
                    v += __shfl_xor(v, 1);
                    v += __shfl_xor(v, 2);
                    v += __shfl_xor(v, 4);
                    v += __shfl_xor(v, 8);
                    if (lo == 0) atomicAdd(yp + mh * 16 + j, v);
                }
        }
        // no barrier: next iter's bufIn writes are fenced from this iter's
        // bufIn reads by barriers B,C; pl next-write is fenced by A,B.
    }
}

// ---------------------------------------------------------------------------
// kEmbW: 8 segments/block: emb_s = (Y_s/den) @ Wv + (den/max(den,eps))*bv
//        + fused w_i = e_i / max(D[sid_i], eps) (grid-stride tail)
// ---------------------------------------------------------------------------
__global__ __launch_bounds__(256) void kEmbW(const float* __restrict__ Y,
                                             const float* __restrict__ D,
                                             const float* __restrict__ Wkv,
                                             const float* __restrict__ bkv,
                                             const float* __restrict__ e,
                                             const int* __restrict__ segids,
                                             float* __restrict__ emb,
                                             float* __restrict__ wout, int nobj) {
    __shared__ float ysh[8][256];
    __shared__ float sw[8];
    const int t = threadIdx.x;
    const int s0 = blockIdx.x * 8;
#pragma unroll
    for (int i = 0; i < 8; ++i) {
        float d = D[s0 + i];
        float dm = fmaxf(d, 1e-9f);
        ysh[i][t] = Y[(size_t)(s0 + i) * 256 + t] / dm;
        if (t == 0) sw[i] = d / dm;
    }
    __syncthreads();
    float acc[8] = {0.f, 0.f, 0.f, 0.f, 0.f, 0.f, 0.f, 0.f};
    for (int h = 0; h < 256; ++h) {
        float wv = Wkv[(size_t)h * 512 + 256 + t];  // fp32 V weights (accuracy)
#pragma unroll
        for (int i = 0; i < 8; ++i) acc[i] += ysh[i][h] * wv;
    }
    float bv = bkv[256 + t];
#pragma unroll
    for (int i = 0; i < 8; ++i) emb[(size_t)(s0 + i) * 256 + t] = acc[i] + sw[i] * bv;

    // fused w output
    for (int i = blockIdx.x * 256 + t; i < nobj; i += gridDim.x * 256)
        wout[i] = e[i] / fmaxf(D[segids[i]], 1e-9f);
}

// ---------------------------------------------------------------------------
extern "C" void kernel_launch(void* const* d_in, const int* in_sizes, int n_in,
                              void* d_out, int out_size, void* d_ws, size_t ws_size,
                              hipStream_t stream) {
    const float* objects = (const float*)d_in[0];
    const float* context = (const float*)d_in[1];
    const int* segids    = (const int*)d_in[2];
    const float* W0  = (const float*)d_in[4];
    const float* b0  = (const float*)d_in[5];
    const float* W1  = (const float*)d_in[6];
    const float* b1  = (const float*)d_in[7];
    const float* Wkv = (const float*)d_in[8];
    const float* bkv = (const float*)d_in[9];
    const float* Wq  = (const float*)d_in[10];
    const float* bq  = (const float*)d_in[11];

    const int NT = in_sizes[2];        // 262144
    const int B  = in_sizes[1] / 256;  // 4096

    char* wsb = (char*)d_ws;
    short* W0f  = (short*)(wsb + 0);        // 64 KB
    short* W1f  = (short*)(wsb + 65536);    // 128 KB
    short* Wkvb = (short*)(wsb + 196608);   // 256 KB
    short* Wqt  = (short*)(wsb + 458752);   // 128 KB
    float* u_ws = (float*)(wsb + 589824);   // 4 MB
    float* c_ws = (float*)(wsb + 4784128);  // 16 KB
    float* e_ws = (float*)(wsb + 4800512);  // 1 MB
    float* Y    = (float*)(wsb + 5849088);  // 4 MB
    float* D    = (float*)(wsb + 10043392); // 16 KB

    float* emb_out = (float*)d_out;
    float* w_out   = (float*)d_out + (size_t)B * 256;

    hipMemsetAsync(wsb + 5849088, 0, 4194304 + 16384, stream);  // zero Y, D
    kPrep0<<<512, 256, 0, stream>>>(W0, W1, Wkv, Wq, W0f, W1f, Wkvb, Wqt);
    kPrep1<<<B / 64, 256, 0, stream>>>(context, Wqt, bq, Wkvb, bkv, u_ws, c_ws);
    kA<<<NT / 256, 256, 0, stream>>>(objects, segids, W0f, W1f, b0, b1, u_ws, c_ws, e_ws, Y, D);
    kEmbW<<<B / 8, 256, 0, stream>>>(Y, D, Wkv, bkv, e_ws, segids, emb_out, w_out, NT);
}

// Round 8
// 136.978 us; speedup vs baseline: 4.5464x; 4.5464x over previous
//
#include <hip/hip_runtime.h>
#include <hip/hip_bf16.h>

// ObjectSelector: fused MLP -> segment softmax -> segment-weighted embedding.
// Algebra: logit_i = x2_i . u_{s_i} + c_{s_i}   (u_s = Wk @ q_s, c_s = bk.q_s, /16 folded in)
//          emb_s   = (sum_i e_i x2_i)/den @ Wv + bv     (linearity of V-projection)
// kA computes GEMM1/GEMM2 TRANSPOSED (x^T = W^T @ obj^T) so the MFMA C-fragment's
// j-contiguous dim is H -> epilogue stores are ds_write_b64 in natural [m][h] layout,
// and the next GEMM's activation operand reads are natural ds_read_b128.
// R8 (base = R6 verified 136us): Y/D reduce restructured as a statically
// unrolled 64-row loop (independent ds_reads, pipelined) with wave-uniform
// run-boundary flushes -- replaces the dynamic-bound latency-serialized loop.
// R7 lesson: NO cross-tile register staging (loop-carried regs -> scratch spills).

typedef __attribute__((ext_vector_type(8))) short bf16x8;
typedef __attribute__((ext_vector_type(4))) float f32x4;
typedef __attribute__((ext_vector_type(4))) short s16x4;

__device__ __forceinline__ float b2f(short s) {
    unsigned int u = ((unsigned int)(unsigned short)s) << 16;
    float f;
    __builtin_memcpy(&f, &u, 4);
    return f;
}
__device__ __forceinline__ short f2b(float x) {
    __hip_bfloat16 h = __float2bfloat16(x);
    short s;
    __builtin_memcpy(&s, &h, 2);
    return s;
}
__device__ __forceinline__ unsigned pack2(float a, float b) {
    return ((unsigned)(unsigned short)f2b(a)) | (((unsigned)(unsigned short)f2b(b)) << 16);
}
__device__ __forceinline__ f32x4 vmax0(f32x4 v) {
    f32x4 r;
    r[0] = fmaxf(v[0], 0.f); r[1] = fmaxf(v[1], 0.f);
    r[2] = fmaxf(v[2], 0.f); r[3] = fmaxf(v[3], 0.f);
    return r;
}

#define MFMA16(a, b, c) __builtin_amdgcn_mfma_f32_16x16x32_bf16(a, b, c, 0, 0, 0)
#define SWZ(row) (((row) & 7) << 4)   // XOR-swizzle on 16B chunks (G4 bank-conflict fix)

// ---------------------------------------------------------------------------
// prep0: weights -> bf16.
//  W0f: frag-ordered W0^T: i = (((w*4+mh)*4+ks)*64+lane)*8+e
//       value = W0[k][h], h=w*64+mh*16+(lane&15), k=ks*32+(lane>>4)*8+e
//  W1f: frag-ordered W1^T: i = (((w*4+mh)*8+ks)*64+lane)*8+e  (same mapping, K=256)
//  Wqt[n][k] (256x256), Wkvb straight copy (256x512)   (for kPrep1)
// ---------------------------------------------------------------------------
__global__ void kPrep0(const float* __restrict__ W0, const float* __restrict__ W1,
                       const float* __restrict__ Wkv, const float* __restrict__ Wq,
                       short* __restrict__ W0f, short* __restrict__ W1f,
                       short* __restrict__ Wkvb, short* __restrict__ Wqt) {
    int i = blockIdx.x * 256 + threadIdx.x;  // grid covers 131072
    if (i < 32768) {
        int e = i & 7, lane = (i >> 3) & 63, ks = (i >> 9) & 3, mh = (i >> 11) & 3, wv = (i >> 13) & 3;
        int h = wv * 64 + mh * 16 + (lane & 15);
        int k = ks * 32 + (lane >> 4) * 8 + e;
        W0f[i] = f2b(W0[k * 256 + h]);
    }
    if (i < 65536) {
        int e = i & 7, lane = (i >> 3) & 63, ks = (i >> 9) & 7, mh = (i >> 12) & 3, wv = (i >> 14) & 3;
        int h = wv * 64 + mh * 16 + (lane & 15);
        int k = ks * 32 + (lane >> 4) * 8 + e;
        W1f[i] = f2b(W1[k * 256 + h]);
        int n = i >> 8, kk = i & 255;
        Wqt[i] = f2b(Wq[kk * 256 + n]);
    }
    if (i < 131072) Wkvb[i] = f2b(Wkv[i]);
}

// ---------------------------------------------------------------------------
// prep1: per 64 context rows: q = ctx@Wq + bq; c = (q.bk)/16; u = (q@Wk^T)/16
// ---------------------------------------------------------------------------
__global__ __launch_bounds__(256) void kPrep1(
        const float* __restrict__ context, const short* __restrict__ Wqt,
        const float* __restrict__ bq, const short* __restrict__ Wkvb,
        const float* __restrict__ bkv, float* __restrict__ u_ws,
        float* __restrict__ c_ws) {
    __shared__ short cbuf[64 * 256];
    __shared__ float pl[4][64];
    const int t = threadIdx.x, w = t >> 6, l = t & 63;
    const int lo = l & 15, hi = l >> 4;
    const int base = blockIdx.x * 64;

    const float* src = context + (size_t)base * 256;
#pragma unroll
    for (int i = 0; i < 16; ++i) {
        int fi = (t + i * 256) * 4;
        float4 v = *(const float4*)(src + fi);
        int row = fi >> 8, col = fi & 255;
        int byte = (row << 9) + (col << 1);
        byte ^= SWZ(row);
        s16x4 pk;
        pk[0] = f2b(v.x); pk[1] = f2b(v.y); pk[2] = f2b(v.z); pk[3] = f2b(v.w);
        *(s16x4*)((char*)cbuf + byte) = pk;
    }
    __syncthreads();

    f32x4 acc[4][4] = {};
    const short* wqb = Wqt + (size_t)(w * 64 + lo) * 256 + hi * 8;
#pragma unroll
    for (int ks = 0; ks < 8; ++ks) {
        bf16x8 a[4], b[4];
#pragma unroll
        for (int m = 0; m < 4; ++m) {
            int row = m * 16 + lo;
            int byte = (row << 9) + ks * 64 + hi * 16;
            byte ^= SWZ(row);
            a[m] = *(const bf16x8*)((const char*)cbuf + byte);
        }
#pragma unroll
        for (int n = 0; n < 4; ++n) b[n] = *(const bf16x8*)(wqb + n * 16 * 256 + ks * 32);
#pragma unroll
        for (int m = 0; m < 4; ++m)
#pragma unroll
            for (int n = 0; n < 4; ++n) acc[m][n] = MFMA16(a[m], b[n], acc[m][n]);
    }
    __syncthreads();

    float bqv[4];
#pragma unroll
    for (int n = 0; n < 4; ++n) bqv[n] = bq[w * 64 + n * 16 + lo];
#pragma unroll
    for (int m = 0; m < 4; ++m)
#pragma unroll
        for (int n = 0; n < 4; ++n)
#pragma unroll
            for (int j = 0; j < 4; ++j) {
                float q = acc[m][n][j] + bqv[n];
                int row = m * 16 + hi * 4 + j;
                int col = w * 64 + n * 16 + lo;
                int byte = (row << 9) + (col << 1);
                byte ^= SWZ(row);
                *(short*)((char*)cbuf + byte) = f2b(q);
            }
    __syncthreads();

    {
        float p = 0.f;
#pragma unroll
        for (int j = 0; j < 8; ++j) {
            int col = w * 64 + j * 8;
            int byte = (l << 9) + (col << 1);
            byte ^= SWZ(l);
            bf16x8 xv = *(const bf16x8*)((const char*)cbuf + byte);
            const float* bp = bkv + col;
            p += b2f(xv[0]) * bp[0] + b2f(xv[1]) * bp[1] + b2f(xv[2]) * bp[2] + b2f(xv[3]) * bp[3]
               + b2f(xv[4]) * bp[4] + b2f(xv[5]) * bp[5] + b2f(xv[6]) * bp[6] + b2f(xv[7]) * bp[7];
        }
        pl[w][l] = p;
    }
    __syncthreads();
    if (t < 64) c_ws[base + t] = (pl[0][t] + pl[1][t] + pl[2][t] + pl[3][t]) * 0.0625f;

#pragma unroll
    for (int m = 0; m < 4; ++m)
#pragma unroll
        for (int n = 0; n < 4; ++n) acc[m][n] = (f32x4){0.f, 0.f, 0.f, 0.f};
    const short* wkb = Wkvb + (size_t)(w * 64 + lo) * 512 + hi * 8;
#pragma unroll
    for (int ks = 0; ks < 8; ++ks) {
        bf16x8 a[4], b[4];
#pragma unroll
        for (int m = 0; m < 4; ++m) {
            int row = m * 16 + lo;
            int byte = (row << 9) + ks * 64 + hi * 16;
            byte ^= SWZ(row);
            a[m] = *(const bf16x8*)((const char*)cbuf + byte);
        }
#pragma unroll
        for (int n = 0; n < 4; ++n) b[n] = *(const bf16x8*)(wkb + n * 16 * 512 + ks * 32);
#pragma unroll
        for (int m = 0; m < 4; ++m)
#pragma unroll
            for (int n = 0; n < 4; ++n) acc[m][n] = MFMA16(a[m], b[n], acc[m][n]);
    }
#pragma unroll
    for (int m = 0; m < 4; ++m)
#pragma unroll
        for (int n = 0; n < 4; ++n)
#pragma unroll
            for (int j = 0; j < 4; ++j) {
                int s = base + m * 16 + hi * 4 + j;
                int col = w * 64 + n * 16 + lo;
                u_ws[(size_t)s * 256 + col] = acc[m][n][j] * 0.0625f;
            }
}

// ---------------------------------------------------------------------------
// kernel A (transposed-MFMA): per 64 objects.
//  acc[mh][nn]: lane holds x for m = nn*16+(l&15), h = w*64+mh*16+(l>>4)*4+j.
// LDS: bufIn 16K [0,16K) | x1 32K [16K,48K) | x2 32K [0,32K) after barrier 3.
// 4 barriers. XCD-chunked tile swizzle; vector epilogues; unrolled flush-reduce.
// ---------------------------------------------------------------------------
__global__ __launch_bounds__(256, 3) void kA(
        const float* __restrict__ objects, const int* __restrict__ segids,
        const short* __restrict__ W0f, const short* __restrict__ W1f,
        const float* __restrict__ b0, const float* __restrict__ b1,
        const float* __restrict__ u_ws, const float* __restrict__ c_ws,
        float* __restrict__ e_ws, float* __restrict__ Y, float* __restrict__ D) {
    __shared__ char smem[49152];
    __shared__ float pl[4][64];
    __shared__ float e_sh[64];
    __shared__ int sid_sh[64];
    char* bufIn = smem;           // objects bf16 [64][128], dead after GEMM1
    char* x1b   = smem + 16384;   // x1 bf16 [64][256], dead after GEMM2
    char* x2b   = smem;           // x2 bf16 [64][256], written after barrier 3

    const int t = threadIdx.x, w = t >> 6, l = t & 63;
    const int lo = l & 15, hi = l >> 4;
    // T1: XCD-chunked swizzle — each XCD gets a contiguous tile chunk (4096%8==0)
    const int bid = (blockIdx.x & 7) * (gridDim.x >> 3) + (blockIdx.x >> 3);
    const size_t base_row = (size_t)bid * 64;

    if (t < 64) sid_sh[t] = segids[base_row + t];

    // hoist GEMM1 weight A-frags: their L2 latency overlaps the HBM staging below
    bf16x8 w0frag[4][4];  // [mh][ks]
#pragma unroll
    for (int mh = 0; mh < 4; ++mh)
#pragma unroll
        for (int ks = 0; ks < 4; ++ks)
            w0frag[mh][ks] = *(const bf16x8*)(W0f + ((((w * 4 + mh) * 4 + ks) << 9) + (l << 3)));

    // stage objects 64x128 fp32 -> bf16 swizzled
    const float* src = objects + base_row * 128;
#pragma unroll
    for (int i = 0; i < 8; ++i) {
        int fi = (t + i * 256) * 4;
        float4 v = *(const float4*)(src + fi);
        int row = fi >> 7, col = fi & 127;
        int byte = (row << 8) + (col << 1);
        byte ^= SWZ(row);
        uint2 pk;
        pk.x = pack2(v.x, v.y);
        pk.y = pack2(v.z, v.w);
        *(uint2*)(bufIn + byte) = pk;
    }
    __syncthreads();  // barrier 1: bufIn ready

    // GEMM1 (transposed): x1^T = W0^T @ obj^T.  A = hoisted frags, B = bufIn rows.
    f32x4 acc[4][4] = {};
#pragma unroll
    for (int ks = 0; ks < 4; ++ks) {
        bf16x8 bv[4];
#pragma unroll
        for (int nn = 0; nn < 4; ++nn) {
            int m = nn * 16 + lo;
            int byte = (m << 8) + (ks << 6) + (hi << 4);
            byte ^= SWZ(m);
            bv[nn] = *(const bf16x8*)(bufIn + byte);
        }
        __builtin_amdgcn_s_setprio(1);
#pragma unroll
        for (int mh = 0; mh < 4; ++mh)
#pragma unroll
            for (int nn = 0; nn < 4; ++nn) acc[mh][nn] = MFMA16(w0frag[mh][ks], bv[nn], acc[mh][nn]);
        __builtin_amdgcn_s_setprio(0);
    }

    // epilogue 1: x1[m][h] = relu(x + b0) — vector ops, b64 stores
#pragma unroll
    for (int mh = 0; mh < 4; ++mh) {
        f32x4 bb = *(const f32x4*)(b0 + w * 64 + mh * 16 + hi * 4);
#pragma unroll
        for (int nn = 0; nn < 4; ++nn) {
            f32x4 v = vmax0(acc[mh][nn] + bb);
            int m = nn * 16 + lo;
            int byte = (m << 9) + ((w * 64 + mh * 16 + hi * 4) << 1);
            byte ^= SWZ(m);
            uint2 pk;
            pk.x = pack2(v[0], v[1]);
            pk.y = pack2(v[2], v[3]);
            *(uint2*)(x1b + byte) = pk;
        }
    }
    __syncthreads();  // barrier 2: x1 ready

    // GEMM2 (transposed): x2^T = W1^T @ x1^T.  A = W1f frags, B = x1 rows (b128).
#pragma unroll
    for (int mh = 0; mh < 4; ++mh)
#pragma unroll
        for (int nn = 0; nn < 4; ++nn) acc[mh][nn] = (f32x4){0.f, 0.f, 0.f, 0.f};
#pragma unroll
    for (int ks = 0; ks < 8; ++ks) {
        bf16x8 av[4], bv[4];
#pragma unroll
        for (int mh = 0; mh < 4; ++mh)
            av[mh] = *(const bf16x8*)(W1f + ((((w * 4 + mh) * 8 + ks) << 9) + (l << 3)));
#pragma unroll
        for (int nn = 0; nn < 4; ++nn) {
            int m = nn * 16 + lo;
            int byte = (m << 9) + (ks << 6) + (hi << 4);
            byte ^= SWZ(m);
            bv[nn] = *(const bf16x8*)(x1b + byte);
        }
        __builtin_amdgcn_s_setprio(1);
#pragma unroll
        for (int mh = 0; mh < 4; ++mh)
#pragma unroll
            for (int nn = 0; nn < 4; ++nn) acc[mh][nn] = MFMA16(av[mh], bv[nn], acc[mh][nn]);
        __builtin_amdgcn_s_setprio(0);
    }

    // epilogue 2: bias+relu in acc (vector), fused logit partials (vector acc)
    int sids[4];
#pragma unroll
    for (int nn = 0; nn < 4; ++nn) sids[nn] = sid_sh[nn * 16 + lo];
    f32x4 pacc[4] = {};
#pragma unroll
    for (int mh = 0; mh < 4; ++mh) {
        f32x4 bb = *(const f32x4*)(b1 + w * 64 + mh * 16 + hi * 4);
#pragma unroll
        for (int nn = 0; nn < 4; ++nn) {
            f32x4 u4 = *(const f32x4*)(u_ws + (size_t)sids[nn] * 256 + w * 64 + mh * 16 + hi * 4);
            f32x4 v = vmax0(acc[mh][nn] + bb);
            acc[mh][nn] = v;
            pacc[nn] += v * u4;
        }
    }
    // horizontal + cross-hi reduce of logit partials (lanes l, l^16, l^32, l^48)
#pragma unroll
    for (int nn = 0; nn < 4; ++nn) {
        float p = (pacc[nn][0] + pacc[nn][1]) + (pacc[nn][2] + pacc[nn][3]);
        p += __shfl_xor(p, 16);
        p += __shfl_xor(p, 32);
        if (hi == 0) pl[w][nn * 16 + lo] = p;
    }
    __syncthreads();  // barrier 3: x1/bufIn dead; pl published

    // wave 0 computes e and publishes to e_sh (ready at barrier 4)
    if (t < 64) {
        float logit = pl[0][t] + pl[1][t] + pl[2][t] + pl[3][t] + c_ws[sid_sh[t]];
        float e = __expf(logit);  // logits tiny: no max-subtraction needed
        e_sh[t] = e;
        e_ws[base_row + t] = e;
    }

    // store x2 (overlays bufIn + x1 low half)
#pragma unroll
    for (int mh = 0; mh < 4; ++mh) {
#pragma unroll
        for (int nn = 0; nn < 4; ++nn) {
            int m = nn * 16 + lo;
            int byte = (m << 9) + ((w * 64 + mh * 16 + hi * 4) << 1);
            byte ^= SWZ(m);
            uint2 pk;
            pk.x = pack2(acc[mh][nn][0], acc[mh][nn][1]);
            pk.y = pack2(acc[mh][nn][2], acc[mh][nn][3]);
            *(uint2*)(x2b + byte) = pk;
        }
    }
    __syncthreads();  // barrier 4: x2 + e_sh ready

    // Y/D reduce: statically unrolled over all 64 rows; independent ds_reads
    // pipeline; flush at run boundaries (wave-uniform branch, segments sorted).
    {
        float ysum = 0.f, dsum = 0.f;
#pragma unroll
        for (int r = 0; r < 64; ++r) {
            float er = e_sh[r];
            int byte = ((r << 9) + (t << 1)) ^ SWZ(r);
            ysum += er * b2f(*(const short*)(x2b + byte));
            dsum += er;
            if ((r == 63) || (sid_sh[r + 1] != sid_sh[r])) {  // uniform flush
                int s = sid_sh[r];
                atomicAdd(Y + (size_t)s * 256 + t, ysum);
                if (t == 0) atomicAdd(D + s, dsum);
                ysum = 0.f;
                dsum = 0.f;
            }
        }
    }
}

// ---------------------------------------------------------------------------
// kEmbW: 8 segments/block: emb_s = (Y_s/den) @ Wv + (den/max(den,eps))*bv
//        + fused w_i = e_i / max(D[sid_i], eps) (grid-stride tail)
// ---------------------------------------------------------------------------
__global__ __launch_bounds__(256) void kEmbW(const float* __restrict__ Y,
                                             const float* __restrict__ D,
                                             const float* __restrict__ Wkv,
                                             const float* __restrict__ bkv,
                                             const float* __restrict__ e,
                                             const int* __restrict__ segids,
                                             float* __restrict__ emb,
                                             float* __restrict__ wout, int nobj) {
    __shared__ float ysh[8][256];
    __shared__ float sw[8];
    const int t = threadIdx.x;
    const int s0 = blockIdx.x * 8;
#pragma unroll
    for (int i = 0; i < 8; ++i) {
        float d = D[s0 + i];
        float dm = fmaxf(d, 1e-9f);
        ysh[i][t] = Y[(size_t)(s0 + i) * 256 + t] / dm;
        if (t == 0) sw[i] = d / dm;
    }
    __syncthreads();
    float acc[8] = {0.f, 0.f, 0.f, 0.f, 0.f, 0.f, 0.f, 0.f};
    for (int h = 0; h < 256; ++h) {
        float wv = Wkv[(size_t)h * 512 + 256 + t];  // fp32 V weights (accuracy)
#pragma unroll
        for (int i = 0; i < 8; ++i) acc[i] += ysh[i][h] * wv;
    }
    float bv = bkv[256 + t];
#pragma unroll
    for (int i = 0; i < 8; ++i) emb[(size_t)(s0 + i) * 256 + t] = acc[i] + sw[i] * bv;

    // fused w output
    for (int i = blockIdx.x * 256 + t; i < nobj; i += gridDim.x * 256)
        wout[i] = e[i] / fmaxf(D[segids[i]], 1e-9f);
}

// ---------------------------------------------------------------------------
extern "C" void kernel_launch(void* const* d_in, const int* in_sizes, int n_in,
                              void* d_out, int out_size, void* d_ws, size_t ws_size,
                              hipStream_t stream) {
    const float* objects = (const float*)d_in[0];
    const float* context = (const float*)d_in[1];
    const int* segids    = (const int*)d_in[2];
    const float* W0  = (const float*)d_in[4];
    const float* b0  = (const float*)d_in[5];
    const float* W1  = (const float*)d_in[6];
    const float* b1  = (const float*)d_in[7];
    const float* Wkv = (const float*)d_in[8];
    const float* bkv = (const float*)d_in[9];
    const float* Wq  = (const float*)d_in[10];
    const float* bq  = (const float*)d_in[11];

    const int NT = in_sizes[2];        // 262144
    const int B  = in_sizes[1] / 256;  // 4096

    char* wsb = (char*)d_ws;
    short* W0f  = (short*)(wsb + 0);        // 64 KB
    short* W1f  = (short*)(wsb + 65536);    // 128 KB
    short* Wkvb = (short*)(wsb + 196608);   // 256 KB
    short* Wqt  = (short*)(wsb + 458752);   // 128 KB
    float* u_ws = (float*)(wsb + 589824);   // 4 MB
    float* c_ws = (float*)(wsb + 4784128);  // 16 KB
    float* e_ws = (float*)(wsb + 4800512);  // 1 MB
    float* Y    = (float*)(wsb + 5849088);  // 4 MB
    float* D    = (float*)(wsb + 10043392); // 16 KB

    float* emb_out = (float*)d_out;
    float* w_out   = (float*)d_out + (size_t)B * 256;

    hipMemsetAsync(wsb + 5849088, 0, 4194304 + 16384, stream);  // zero Y, D
    kPrep0<<<512, 256, 0, stream>>>(W0, W1, Wkv, Wq, W0f, W1f, Wkvb, Wqt);
    kPrep1<<<B / 64, 256, 0, stream>>>(context, Wqt, bq, Wkvb, bkv, u_ws, c_ws);
    kA<<<NT / 64, 256, 0, stream>>>(objects, segids, W0f, W1f, b0, b1, u_ws, c_ws, e_ws, Y, D);
    kEmbW<<<B / 8, 256, 0, stream>>>(Y, D, Wkv, bkv, e_ws, segids, emb_out, w_out, NT);
}